// Round 3
// baseline (57128.119 us; speedup 1.0000x reference)
//
#include <hip/hip_runtime.h>

#define NWG   256
#define NTHR  1024
#define STEPS 511

typedef float f4v __attribute__((ext_vector_type(4)));

// ---------------- workspace layout (bytes) ----------------
static constexpr size_t OFF_EKT  = 0;                                   // f32 ekT[64][512][512]
static constexpr size_t OFF_WCT  = OFF_EKT  + (size_t)64*512*512*4;     // f32 WcT[1536][256]
static constexpr size_t OFF_BC   = OFF_WCT  + (size_t)1536*256*4;       // f32 bc[1536]
static constexpr size_t OFF_WHHT = OFF_BC   + (size_t)2048*4;           // f32 WhhT[1536][512]
static constexpr size_t OFF_WQT  = OFF_WHHT + (size_t)1536*512*4;       // f32 WqT[512][512]
static constexpr size_t OFF_H0   = OFF_WQT  + (size_t)512*512*4;        // f32 h0[64][512]
static constexpr size_t OFF_H1   = OFF_H0   + (size_t)64*512*4;         // f32 h1[64][512]
static constexpr size_t OFF_Q    = OFF_H1   + (size_t)64*512*4;         // f32 q[64][512]
static constexpr size_t OFF_AMAX = OFF_Q    + (size_t)64*512*4;         // u64 amax[64]
static constexpr size_t OFF_BAR  = OFF_AMAX + (size_t)64*8;             // u32 bar[2]
static constexpr size_t WS_NEED  = OFF_BAR + 256;

// ---------------- device helpers ----------------
__device__ __forceinline__ float fast_sig(float x) {
  return __builtin_amdgcn_rcpf(1.0f + __expf(-x));
}
__device__ __forceinline__ float fast_tanh(float x) {
  float e = __expf(2.0f * x);
  return 1.0f - 2.0f * __builtin_amdgcn_rcpf(e + 1.0f);
}
__device__ __forceinline__ float ld_sc(const float* p) {
  return __hip_atomic_load(p, __ATOMIC_RELAXED, __HIP_MEMORY_SCOPE_AGENT);
}
__device__ __forceinline__ unsigned long long ld_sc64(const void* p) {
  return __hip_atomic_load((const unsigned long long*)p, __ATOMIC_RELAXED, __HIP_MEMORY_SCOPE_AGENT);
}
__device__ __forceinline__ void st_sc(float* p, float v) {
  __hip_atomic_store(p, v, __ATOMIC_RELAXED, __HIP_MEMORY_SCOPE_AGENT);
}
__device__ __forceinline__ void st_sc64(unsigned long long* p, unsigned long long v) {
  __hip_atomic_store(p, v, __ATOMIC_RELAXED, __HIP_MEMORY_SCOPE_AGENT);
}
__device__ __forceinline__ float u_lo(unsigned long long u){ return __uint_as_float((unsigned)u); }
__device__ __forceinline__ float u_hi(unsigned long long u){ return __uint_as_float((unsigned)(u >> 32)); }
__device__ __forceinline__ f4v ntld(const float* p) {
  return __builtin_nontemporal_load((const f4v*)p);
}

// monotonic-epoch grid barrier (all NWG workgroups co-resident via cooperative launch)
__device__ __forceinline__ void gridbar(unsigned* bar, unsigned& epoch) {
  asm volatile("s_waitcnt vmcnt(0)" ::: "memory");
  __syncthreads();
  epoch++;
  if (threadIdx.x == 0) {
    unsigned old = __hip_atomic_fetch_add(&bar[0], 1u, __ATOMIC_RELAXED, __HIP_MEMORY_SCOPE_AGENT);
    if (old == epoch * NWG - 1u) {
      __hip_atomic_store(&bar[1], epoch, __ATOMIC_RELAXED, __HIP_MEMORY_SCOPE_AGENT);
    } else {
      while (__hip_atomic_load(&bar[1], __ATOMIC_RELAXED, __HIP_MEMORY_SCOPE_AGENT) < epoch)
        __builtin_amdgcn_s_sleep(1);
    }
  }
  __syncthreads();
}

// ---------------- precompute kernels ----------------
__global__ void initk(const float* __restrict__ eh, float* __restrict__ h0,
                      unsigned long long* __restrict__ amax, unsigned* __restrict__ bar) {
  int i = blockIdx.x * blockDim.x + threadIdx.x;
  if (i < 64 * 512) h0[i] = eh[i];
  if (i < 64) amax[i] = 0x00000000FFFFFFFFULL;          // unpacks to idx = 0
  if (i == 0) { bar[0] = 0u; bar[1] = 0u; }
}

__global__ void bck(const float* __restrict__ b_lin, const float* __restrict__ W_ih,
                    const float* __restrict__ b_ih, float* __restrict__ bc) {
  int c = blockIdx.x * 256 + threadIdx.x;
  if (c >= 1536) return;
  float s = b_ih[c];
  for (int k = 0; k < 512; ++k) s += b_lin[k] * W_ih[k * 1536 + c];
  bc[c] = s;
}

__global__ void trk(const float* __restrict__ in, float* __restrict__ out, int R, int C) {
  int i = blockIdx.x * 256 + threadIdx.x;
  if (i >= R * C) return;
  int r = i / C, c = i % C;
  out[(size_t)c * R + r] = in[i];
}

__global__ __launch_bounds__(256) void gemm64(const float* __restrict__ A, const float* __restrict__ B,
                                              float* __restrict__ C, int K, int lda, int ldb,
                                              int mode, int N) {
  __shared__ float As[16][65];
  __shared__ float Bs[16][65];
  const int t = threadIdx.x;
  const int r0 = blockIdx.x * 64, n0 = blockIdx.y * 64;
  const int tx = t & 15, ty = t >> 4;
  const int am = t >> 2, ak = (t & 3) * 4;
  const int bk = t >> 4, bn = (t & 15) * 4;
  float acc[4][4] = {};
  for (int k0 = 0; k0 < K; k0 += 16) {
    float4 av = *(const float4*)&A[(size_t)(r0 + am) * lda + k0 + ak];
    float4 bv = *(const float4*)&B[(size_t)(k0 + bk) * ldb + n0 + bn];
    As[ak + 0][am] = av.x; As[ak + 1][am] = av.y; As[ak + 2][am] = av.z; As[ak + 3][am] = av.w;
    Bs[bk][bn + 0] = bv.x; Bs[bk][bn + 1] = bv.y; Bs[bk][bn + 2] = bv.z; Bs[bk][bn + 3] = bv.w;
    __syncthreads();
#pragma unroll
    for (int k = 0; k < 16; ++k) {
      float a0 = As[k][ty * 4 + 0], a1 = As[k][ty * 4 + 1], a2 = As[k][ty * 4 + 2], a3 = As[k][ty * 4 + 3];
      float b0 = Bs[k][tx * 4 + 0], b1 = Bs[k][tx * 4 + 1], b2 = Bs[k][tx * 4 + 2], b3 = Bs[k][tx * 4 + 3];
      acc[0][0] += a0 * b0; acc[0][1] += a0 * b1; acc[0][2] += a0 * b2; acc[0][3] += a0 * b3;
      acc[1][0] += a1 * b0; acc[1][1] += a1 * b1; acc[1][2] += a1 * b2; acc[1][3] += a1 * b3;
      acc[2][0] += a2 * b0; acc[2][1] += a2 * b1; acc[2][2] += a2 * b2; acc[2][3] += a2 * b3;
      acc[3][0] += a3 * b0; acc[3][1] += a3 * b1; acc[3][2] += a3 * b2; acc[3][3] += a3 * b3;
    }
    __syncthreads();
  }
#pragma unroll
  for (int i = 0; i < 4; ++i)
#pragma unroll
    for (int j = 0; j < 4; ++j) {
      int r = r0 + ty * 4 + i, c = n0 + tx * 4 + j;
      if (mode == 1) { int l = r >> 6, bb = r & 63; C[((size_t)bb * 512 + l) * 512 + c] = acc[i][j]; }
      else if (mode == 2) { C[(size_t)c * 256 + r] = acc[i][j]; }
      else { C[(size_t)r * N + c] = acc[i][j]; }
    }
}

// ---------------- the persistent cooperative decoder ----------------
struct CoopArgs {
  const float* inputs;
  const float* b_hh;
  const float* ekT;
  const float* WcT;  const float* bc;
  const float* WhhT; const float* WqT;
  const float* v_att;
  float* h0; float* h1; float* q;
  unsigned long long* amax;
  unsigned* bar;
  float* out;
};

__global__ __launch_bounds__(NTHR, 4) void decoder(CoopArgs a) {
  // 88KB static LDS -> 1 WG/CU; 256 WGs over 256 CUs
  __shared__ float smem[22528];
  float* sred = smem;                                   // [8][8][16][4] floats (16 KB)
  float* h_s  = smem + 4096;                            // [8][516] floats (16.5 KB, padded)
  float* q_s  = smem + 8224;                            // [512]
  int*   s_idx = (int*)(smem + 8736);                   // [8]
  unsigned long long* su64 = (unsigned long long*)(smem + 8744);  // [16] (byte 34976, 8-aligned)

  const int w = blockIdx.x, tid = threadIdx.x;
  const int lane = tid & 63;

  // P3 per-lane constants
  const float4 vA = *(const float4*)&a.v_att[lane * 4];
  const float4 vB = *(const float4*)&a.v_att[256 + lane * 4];

  // P1/P2 decomposition: 256 WGs = 8 b-blocks x 32 j-blocks
  const int jj  = tid & 15, bi8 = (tid >> 4) & 7, ks = tid >> 7;
  const int jb  = w & 31,  bb  = w >> 5;
  const int b1  = bb * 8 + bi8, j1 = jb * 16 + jj;
  (void)b1;
  // P3 decomposition: 256 WGs = 64 b x 4 l-tiles; 16 waves x 8 l each
  const int b3 = w & 63, lt = w >> 6, wv = tid >> 6;
  const float* ekp = a.ekT + ((size_t)b3 * 512 + (size_t)(lt * 128 + wv * 8)) * 512 + lane * 4;

  // weight row pointers (loop-invariant)
  const float* w0 = a.WcT  + (size_t)(j1)        * 256;
  const float* w1 = a.WcT  + (size_t)(512  + j1) * 256;
  const float* w2 = a.WcT  + (size_t)(1024 + j1) * 256;
  const float* u0 = a.WhhT + (size_t)(j1)        * 512;
  const float* u1 = a.WhhT + (size_t)(512  + j1) * 512;
  const float* u2 = a.WhhT + (size_t)(1024 + j1) * 512;
  const float* wq = a.WqT  + (size_t)j1 * 512;
  const float* hrow = &h_s[bi8 * 516];

  // cross-step prefetch registers: 8 rows x (2 x float4) = 64 VGPRs
  f4v pA0, pA1, pA2, pA3, pA4, pA5, pA6, pA7;
  f4v pB0, pB1, pB2, pB3, pB4, pB5, pB6, pB7;
#define ISSUE() do { \
    pA0 = ntld(ekp + 0*512);       pB0 = ntld(ekp + 0*512 + 256); \
    pA1 = ntld(ekp + 1*512);       pB1 = ntld(ekp + 1*512 + 256); \
    pA2 = ntld(ekp + 2*512);       pB2 = ntld(ekp + 2*512 + 256); \
    pA3 = ntld(ekp + 3*512);       pB3 = ntld(ekp + 3*512 + 256); \
    pA4 = ntld(ekp + 4*512);       pB4 = ntld(ekp + 4*512 + 256); \
    pA5 = ntld(ekp + 5*512);       pB5 = ntld(ekp + 5*512 + 256); \
    pA6 = ntld(ekp + 6*512);       pB6 = ntld(ekp + 6*512 + 256); \
    pA7 = ntld(ekp + 7*512);       pB7 = ntld(ekp + 7*512 + 256); \
  } while (0)

  ISSUE();   // prefetch for step 0

  unsigned epoch = 0;

  for (int t = 0; t < STEPS; ++t) {
    float* hcur = (t & 1) ? a.h1 : a.h0;
    float* hnxt = (t & 1) ? a.h0 : a.h1;

    // ================= P1: GRU -> h_new =================
    {
      // stage hcur[bb*8 .. +8][:] (16KB) + amax into LDS (agent-scope loads, once)
      const unsigned long long* hs64 = (const unsigned long long*)hcur + (size_t)bb * 2048;
      {
        unsigned long long v0 = ld_sc64(hs64 + tid);
        unsigned long long v1 = ld_sc64(hs64 + tid + 1024);
        int r0i = tid >> 8,          c0 = (tid & 255) * 2;
        int r1i = (tid + 1024) >> 8, c1 = (tid & 255) * 2;
        h_s[r0i * 516 + c0] = u_lo(v0); h_s[r0i * 516 + c0 + 1] = u_hi(v0);
        h_s[r1i * 516 + c1] = u_lo(v1); h_s[r1i * 516 + c1 + 1] = u_hi(v1);
      }
      if (tid < 8) s_idx[tid] = (int)((~(unsigned)ld_sc64(&a.amax[bb * 8 + tid])) & 511u);
      __syncthreads();

      const int idx = s_idx[bi8];
      const float* xrow = a.inputs + ((size_t)idx * 64 + (bb * 8 + bi8)) * 256;
      float s0 = 0.f, s1 = 0.f, s2 = 0.f, s3 = 0.f;
#pragma unroll
      for (int k = ks * 32; k < ks * 32 + 32; k += 4) {
        float4 xv  = *(const float4*)&xrow[k];
        float4 c0 = *(const float4*)&w0[k];
        float4 c1 = *(const float4*)&w1[k];
        float4 c2 = *(const float4*)&w2[k];
        s0 += xv.x * c0.x + xv.y * c0.y + xv.z * c0.z + xv.w * c0.w;
        s1 += xv.x * c1.x + xv.y * c1.y + xv.z * c1.z + xv.w * c1.w;
        s2 += xv.x * c2.x + xv.y * c2.y + xv.z * c2.z + xv.w * c2.w;
      }
#pragma unroll 4
      for (int k = ks * 64; k < ks * 64 + 64; k += 4) {
        float4 h4 = *(const float4*)&hrow[k];
        float4 c0 = *(const float4*)&u0[k];
        float4 c1 = *(const float4*)&u1[k];
        float4 c2 = *(const float4*)&u2[k];
        s0 += h4.x * c0.x + h4.y * c0.y + h4.z * c0.z + h4.w * c0.w;
        s1 += h4.x * c1.x + h4.y * c1.y + h4.z * c1.z + h4.w * c1.w;
        s3 += h4.x * c2.x + h4.y * c2.y + h4.z * c2.z + h4.w * c2.w;
      }
      *(float4*)&sred[(size_t)((ks * 8 + bi8) * 16 + jj) * 4] = make_float4(s0, s1, s2, s3);
      __syncthreads();
      if (tid < 128) {
        int bi = tid >> 4, j2 = tid & 15;
        float4 acc4 = make_float4(0.f, 0.f, 0.f, 0.f);
#pragma unroll
        for (int kk = 0; kk < 8; ++kk) {
          float4 vv = *(float4*)&sred[(size_t)((kk * 8 + bi) * 16 + j2) * 4];
          acc4.x += vv.x; acc4.y += vv.y; acc4.z += vv.z; acc4.w += vv.w;
        }
        int b = bb * 8 + bi, j = jb * 16 + j2;
        float r = fast_sig(acc4.x + a.bc[j] + a.b_hh[j]);
        float z = fast_sig(acc4.y + a.bc[512 + j] + a.b_hh[512 + j]);
        float n = fast_tanh(acc4.z + a.bc[1024 + j] + r * (acc4.w + a.b_hh[1024 + j]));
        float hv = h_s[bi * 516 + j];
        st_sc(&hnxt[b * 512 + j], (1.f - z) * n + z * hv);
      }
    }
    gridbar(a.bar, epoch);

    // ================= P2: q = h_new @ W_q  (+ amax reset) =================
    {
      const unsigned long long* hs64 = (const unsigned long long*)hnxt + (size_t)bb * 2048;
      {
        unsigned long long v0 = ld_sc64(hs64 + tid);
        unsigned long long v1 = ld_sc64(hs64 + tid + 1024);
        int r0i = tid >> 8,          c0 = (tid & 255) * 2;
        int r1i = (tid + 1024) >> 8, c1 = (tid & 255) * 2;
        h_s[r0i * 516 + c0] = u_lo(v0); h_s[r0i * 516 + c0 + 1] = u_hi(v0);
        h_s[r1i * 516 + c1] = u_lo(v1); h_s[r1i * 516 + c1 + 1] = u_hi(v1);
      }
      __syncthreads();
      float s = 0.f;
#pragma unroll 4
      for (int k = ks * 64; k < ks * 64 + 64; k += 4) {
        float4 h4 = *(const float4*)&hrow[k];
        float4 c4 = *(const float4*)&wq[k];
        s += h4.x * c4.x + h4.y * c4.y + h4.z * c4.z + h4.w * c4.w;
      }
      sred[(ks * 8 + bi8) * 16 + jj] = s;
      __syncthreads();
      if (tid < 128) {
        int bi = tid >> 4, ii = tid & 15;
        float acc = 0.f;
#pragma unroll
        for (int kk = 0; kk < 8; ++kk) acc += sred[(kk * 8 + bi) * 16 + ii];
        st_sc(&a.q[(bb * 8 + bi) * 512 + jb * 16 + ii], acc);
      }
      if (jb == 0 && tid < 8) st_sc64(&a.amax[bb * 8 + tid], 0ULL);
    }
    gridbar(a.bar, epoch);

    // ================= P3: attention scores + logits + argmax =================
    {
      if (tid < 256) {
        unsigned long long qu = ld_sc64(&a.q[b3 * 512 + tid * 2]);
        q_s[tid * 2] = u_lo(qu); q_s[tid * 2 + 1] = u_hi(qu);
      }
      __syncthreads();
      float4 qA = *(const float4*)&q_s[lane * 4];
      float4 qB = *(const float4*)&q_s[256 + lane * 4];
      float s0, s1, s2, s3, s4, s5, s6, s7;
#define ROW(PA, PB, S) { float acc; \
      acc  = fast_tanh(qA.x + PA.x) * vA.x; \
      acc += fast_tanh(qA.y + PA.y) * vA.y; \
      acc += fast_tanh(qA.z + PA.z) * vA.z; \
      acc += fast_tanh(qA.w + PA.w) * vA.w; \
      acc += fast_tanh(qB.x + PB.x) * vB.x; \
      acc += fast_tanh(qB.y + PB.y) * vB.y; \
      acc += fast_tanh(qB.z + PB.z) * vB.z; \
      acc += fast_tanh(qB.w + PB.w) * vB.w; \
      _Pragma("unroll") \
      for (int m = 1; m < 64; m <<= 1) acc += __shfl_xor(acc, m, 64); \
      S = acc; }
      ROW(pA0, pB0, s0) ROW(pA1, pB1, s1) ROW(pA2, pB2, s2) ROW(pA3, pB3, s3)
      ROW(pA4, pB4, s4) ROW(pA5, pB5, s5) ROW(pA6, pB6, s6) ROW(pA7, pB7, s7)
#undef ROW
      if (lane == 0) {
        size_t off = ((size_t)t * 64 + b3) * 512 + (size_t)(lt * 128 + wv * 8);
        *(float4*)&a.out[off]     = make_float4(s0, s1, s2, s3);
        *(float4*)&a.out[off + 4] = make_float4(s4, s5, s6, s7);
        float best = s0; int bu = 0;
        if (s1 > best) { best = s1; bu = 1; }
        if (s2 > best) { best = s2; bu = 2; }
        if (s3 > best) { best = s3; bu = 3; }
        if (s4 > best) { best = s4; bu = 4; }
        if (s5 > best) { best = s5; bu = 5; }
        if (s6 > best) { best = s6; bu = 6; }
        if (s7 > best) { best = s7; bu = 7; }
        unsigned bits = __float_as_uint(best);
        unsigned key  = bits ^ ((bits & 0x80000000u) ? 0xFFFFFFFFu : 0x80000000u);
        unsigned ll   = (unsigned)(lt * 128 + wv * 8 + bu);
        su64[wv] = ((unsigned long long)key << 32) | (unsigned)(~ll);
      }
      ISSUE();          // prefetch for step t+1 (addresses are step-invariant)
      __syncthreads();
      if (tid == 0) {
        unsigned long long m = su64[0];
#pragma unroll
        for (int i = 1; i < 16; ++i) if (su64[i] > m) m = su64[i];
        __hip_atomic_fetch_max(&a.amax[b3], m, __ATOMIC_RELAXED, __HIP_MEMORY_SCOPE_AGENT);
      }
    }
    gridbar(a.bar, epoch);
  }
#undef ISSUE
}

// ---------------- launcher ----------------
extern "C" void kernel_launch(void* const* d_in, const int* in_sizes, int n_in,
                              void* d_out, int out_size, void* d_ws, size_t ws_size,
                              hipStream_t stream) {
  (void)in_sizes; (void)n_in; (void)out_size;
  if (ws_size < WS_NEED) return;

  const float* inputs  = (const float*)d_in[0];
  const float* enc_out = (const float*)d_in[2];
  const float* enc_hid = (const float*)d_in[3];
  const float* W_lin   = (const float*)d_in[4];
  const float* b_lin   = (const float*)d_in[5];
  const float* W_ih    = (const float*)d_in[6];
  const float* W_hh    = (const float*)d_in[7];
  const float* b_ih    = (const float*)d_in[8];
  const float* b_hh    = (const float*)d_in[9];
  const float* W_q     = (const float*)d_in[10];
  const float* W_k     = (const float*)d_in[11];
  const float* v_att   = (const float*)d_in[12];

  char* ws = (char*)d_ws;
  float* ekT  = (float*)(ws + OFF_EKT);
  float* WcT  = (float*)(ws + OFF_WCT);
  float* bc   = (float*)(ws + OFF_BC);
  float* WhhT = (float*)(ws + OFF_WHHT);
  float* WqT  = (float*)(ws + OFF_WQT);
  float* h0   = (float*)(ws + OFF_H0);
  float* h1   = (float*)(ws + OFF_H1);
  float* q    = (float*)(ws + OFF_Q);
  unsigned long long* amax = (unsigned long long*)(ws + OFF_AMAX);
  unsigned* bar = (unsigned*)(ws + OFF_BAR);

  initk<<<dim3(128), dim3(256), 0, stream>>>(enc_hid, h0, amax, bar);
  bck<<<dim3(6), dim3(256), 0, stream>>>(b_lin, W_ih, b_ih, bc);
  trk<<<dim3((512 * 1536 + 255) / 256), dim3(256), 0, stream>>>(W_hh, WhhT, 512, 1536);
  trk<<<dim3((512 * 512 + 255) / 256), dim3(256), 0, stream>>>(W_q, WqT, 512, 512);
  gemm64<<<dim3(4, 24), dim3(256), 0, stream>>>(W_lin, W_ih, WcT, 512, 512, 1536, 2, 1536);
  gemm64<<<dim3(512, 8), dim3(256), 0, stream>>>(enc_out, W_k, ekT, 512, 512, 512, 1, 512);

  CoopArgs ca;
  ca.inputs = inputs; ca.b_hh = b_hh; ca.ekT = ekT;
  ca.WcT = WcT; ca.bc = bc; ca.WhhT = WhhT; ca.WqT = WqT;
  ca.v_att = v_att;
  ca.h0 = h0; ca.h1 = h1; ca.q = q;
  ca.amax = amax; ca.bar = bar;
  ca.out = (float*)d_out;

  void* args[] = { &ca };
  hipLaunchCooperativeKernel((const void*)decoder, dim3(NWG), dim3(NTHR), args, 0, stream);
}

// Round 4
// 26156.952 us; speedup vs baseline: 2.1841x; 2.1841x over previous
//
#include <hip/hip_runtime.h>

#define NWG   256
#define NTHR  1024
#define STEPS 511

typedef float f4v __attribute__((ext_vector_type(4)));

// ---------------- workspace layout (bytes) ----------------
static constexpr size_t OFF_EKT  = 0;                                   // f32 ekT[64][512][512]
static constexpr size_t OFF_WCT  = OFF_EKT  + (size_t)64*512*512*4;     // f32 WcT[1536][256]
static constexpr size_t OFF_BC   = OFF_WCT  + (size_t)1536*256*4;       // f32 bc[1536]
static constexpr size_t OFF_WHHT = OFF_BC   + (size_t)2048*4;           // f32 WhhT[1536][512]
static constexpr size_t OFF_WQT  = OFF_WHHT + (size_t)1536*512*4;       // f32 WqT[512][512]
static constexpr size_t OFF_H0   = OFF_WQT  + (size_t)512*512*4;        // f32 h0[64][512]
static constexpr size_t OFF_H1   = OFF_H0   + (size_t)64*512*4;         // f32 h1[64][512]
static constexpr size_t OFF_Q    = OFF_H1   + (size_t)64*512*4;         // f32 q[64][512]
static constexpr size_t OFF_AMAX = OFF_Q    + (size_t)64*512*4;         // u64 amax[64]
static constexpr size_t OFF_BAR  = OFF_AMAX + (size_t)64*8;             // u32 bar[256] (two-level)
static constexpr size_t WS_NEED  = OFF_BAR + 1024;

// ---------------- device helpers ----------------
__device__ __forceinline__ float fast_sig(float x) {
  return __builtin_amdgcn_rcpf(1.0f + __expf(-x));
}
__device__ __forceinline__ float fast_tanh(float x) {
  float e = __expf(2.0f * x);
  return 1.0f - 2.0f * __builtin_amdgcn_rcpf(e + 1.0f);
}
__device__ __forceinline__ float ld_sc(const float* p) {
  return __hip_atomic_load(p, __ATOMIC_RELAXED, __HIP_MEMORY_SCOPE_AGENT);
}
__device__ __forceinline__ unsigned long long ld_sc64(const void* p) {
  return __hip_atomic_load((const unsigned long long*)p, __ATOMIC_RELAXED, __HIP_MEMORY_SCOPE_AGENT);
}
__device__ __forceinline__ void st_sc(float* p, float v) {
  __hip_atomic_store(p, v, __ATOMIC_RELAXED, __HIP_MEMORY_SCOPE_AGENT);
}
__device__ __forceinline__ void st_sc64(unsigned long long* p, unsigned long long v) {
  __hip_atomic_store(p, v, __ATOMIC_RELAXED, __HIP_MEMORY_SCOPE_AGENT);
}
__device__ __forceinline__ float u_lo(unsigned long long u){ return __uint_as_float((unsigned)u); }
__device__ __forceinline__ float u_hi(unsigned long long u){ return __uint_as_float((unsigned)(u >> 32)); }

// two-level grid barrier: 8 group counters (64B-separated) -> root -> release flag.
// bar[g*16] group counters, bar[128] root, bar[160] release epoch.
__device__ __forceinline__ void gridbar(unsigned* bar, unsigned& epoch, int w) {
  asm volatile("s_waitcnt vmcnt(0)" ::: "memory");   // drain this wave's vmem before arrival
  __syncthreads();
  epoch++;
  if (threadIdx.x == 0) {
    unsigned old = __hip_atomic_fetch_add(&bar[(w >> 5) * 16], 1u,
                                          __ATOMIC_RELAXED, __HIP_MEMORY_SCOPE_AGENT);
    if (old == epoch * 32u - 1u) {
      unsigned oldr = __hip_atomic_fetch_add(&bar[128], 1u,
                                             __ATOMIC_RELAXED, __HIP_MEMORY_SCOPE_AGENT);
      if (oldr == epoch * 8u - 1u)
        __hip_atomic_store(&bar[160], epoch, __ATOMIC_RELAXED, __HIP_MEMORY_SCOPE_AGENT);
    }
    while (__hip_atomic_load(&bar[160], __ATOMIC_RELAXED, __HIP_MEMORY_SCOPE_AGENT) < epoch)
      __builtin_amdgcn_s_sleep(1);
  }
  __syncthreads();
}

// ---------------- precompute kernels ----------------
__global__ void initk(const float* __restrict__ eh, float* __restrict__ h0,
                      unsigned long long* __restrict__ amax, unsigned* __restrict__ bar) {
  int i = blockIdx.x * blockDim.x + threadIdx.x;
  if (i < 64 * 512) h0[i] = eh[i];
  if (i < 64) amax[i] = 0x00000000FFFFFFFFULL;          // unpacks to idx = 0
  if (i < 192) bar[i] = 0u;
}

__global__ void bck(const float* __restrict__ b_lin, const float* __restrict__ W_ih,
                    const float* __restrict__ b_ih, float* __restrict__ bc) {
  int c = blockIdx.x * 256 + threadIdx.x;
  if (c >= 1536) return;
  float s = b_ih[c];
  for (int k = 0; k < 512; ++k) s += b_lin[k] * W_ih[k * 1536 + c];
  bc[c] = s;
}

__global__ void trk(const float* __restrict__ in, float* __restrict__ out, int R, int C) {
  int i = blockIdx.x * 256 + threadIdx.x;
  if (i >= R * C) return;
  int r = i / C, c = i % C;
  out[(size_t)c * R + r] = in[i];
}

__global__ __launch_bounds__(256) void gemm64(const float* __restrict__ A, const float* __restrict__ B,
                                              float* __restrict__ C, int K, int lda, int ldb,
                                              int mode, int N) {
  __shared__ float As[16][65];
  __shared__ float Bs[16][65];
  const int t = threadIdx.x;
  const int r0 = blockIdx.x * 64, n0 = blockIdx.y * 64;
  const int tx = t & 15, ty = t >> 4;
  const int am = t >> 2, ak = (t & 3) * 4;
  const int bk = t >> 4, bn = (t & 15) * 4;
  float acc[4][4] = {};
  for (int k0 = 0; k0 < K; k0 += 16) {
    float4 av = *(const float4*)&A[(size_t)(r0 + am) * lda + k0 + ak];
    float4 bv = *(const float4*)&B[(size_t)(k0 + bk) * ldb + n0 + bn];
    As[ak + 0][am] = av.x; As[ak + 1][am] = av.y; As[ak + 2][am] = av.z; As[ak + 3][am] = av.w;
    Bs[bk][bn + 0] = bv.x; Bs[bk][bn + 1] = bv.y; Bs[bk][bn + 2] = bv.z; Bs[bk][bn + 3] = bv.w;
    __syncthreads();
#pragma unroll
    for (int k = 0; k < 16; ++k) {
      float a0 = As[k][ty * 4 + 0], a1 = As[k][ty * 4 + 1], a2 = As[k][ty * 4 + 2], a3 = As[k][ty * 4 + 3];
      float b0 = Bs[k][tx * 4 + 0], b1 = Bs[k][tx * 4 + 1], b2 = Bs[k][tx * 4 + 2], b3 = Bs[k][tx * 4 + 3];
      acc[0][0] += a0 * b0; acc[0][1] += a0 * b1; acc[0][2] += a0 * b2; acc[0][3] += a0 * b3;
      acc[1][0] += a1 * b0; acc[1][1] += a1 * b1; acc[1][2] += a1 * b2; acc[1][3] += a1 * b3;
      acc[2][0] += a2 * b0; acc[2][1] += a2 * b1; acc[2][2] += a2 * b2; acc[2][3] += a2 * b3;
      acc[3][0] += a3 * b0; acc[3][1] += a3 * b1; acc[3][2] += a3 * b2; acc[3][3] += a3 * b3;
    }
    __syncthreads();
  }
#pragma unroll
  for (int i = 0; i < 4; ++i)
#pragma unroll
    for (int j = 0; j < 4; ++j) {
      int r = r0 + ty * 4 + i, c = n0 + tx * 4 + j;
      if (mode == 1) { int l = r >> 6, bb = r & 63; C[((size_t)bb * 512 + l) * 512 + c] = acc[i][j]; }
      else if (mode == 2) { C[(size_t)c * 256 + r] = acc[i][j]; }
      else { C[(size_t)r * N + c] = acc[i][j]; }
    }
}

// ---------------- the persistent cooperative decoder ----------------
struct CoopArgs {
  const float* inputs;
  const float* b_hh;
  const float* ekT;
  const float* WcT;  const float* bc;
  const float* WhhT; const float* WqT;
  const float* v_att;
  float* h0; float* h1; float* q;
  unsigned long long* amax;
  unsigned* bar;
  float* out;
};

__global__ __launch_bounds__(NTHR, 4) void decoder(CoopArgs a) {
  // ~134 KB static LDS -> 1 WG/CU; 256 WGs over 256 CUs
  __shared__ float smem[33544];
  float* whh_s = smem;                                   // [3*16][516] (99 KB) WhhT slice
  float* sred  = smem + 24768;                           // [8][8][16][4] (16 KB)
  float* h_s   = smem + 28864;                           // [8][516] (16.5 KB)
  float* q_s   = smem + 32992;                           // [512]
  int*   s_idx = (int*)(smem + 33504);                   // [8]
  unsigned long long* su64 = (unsigned long long*)(smem + 33512);  // [16]

  const int w = blockIdx.x, tid = threadIdx.x;
  const int lane = tid & 63;

  // P3 per-lane constants
  const float4 vA = *(const float4*)&a.v_att[lane * 4];
  const float4 vB = *(const float4*)&a.v_att[256 + lane * 4];

  // P1/P2 decomposition: 256 WGs = 8 b-blocks x 32 j-blocks
  const int jj  = tid & 15, bi8 = (tid >> 4) & 7, ks = tid >> 7;
  const int jb  = w & 31,  bb  = w >> 5;
  const int j1  = jb * 16 + jj;
  // P3 decomposition: 256 WGs = 64 b x 4 l-tiles; 16 waves x 8 l each
  const int b3 = w & 63, lt = w >> 6, wv = tid >> 6;
  const float* ekp = a.ekT + ((size_t)b3 * 512 + (size_t)(lt * 128 + wv * 8)) * 512 + lane * 4;

  // stage this WG's WhhT slice (3 gates x 16 rows x 512) into LDS, rows padded to 516
  for (int i4 = tid; i4 < 6144; i4 += NTHR) {
    int g   = i4 >> 11;
    int row = (i4 >> 7) & 15;
    int k4  = (i4 & 127) * 4;
    float4 v = *(const float4*)&a.WhhT[((size_t)(g * 512 + jb * 16 + row)) * 512 + k4];
    *(float4*)&whh_s[(size_t)(g * 16 + row) * 516 + k4] = v;
  }
  __syncthreads();

  // loop-invariant pointers
  const float* w0 = a.WcT  + (size_t)(j1)        * 256;
  const float* w1 = a.WcT  + (size_t)(512  + j1) * 256;
  const float* w2 = a.WcT  + (size_t)(1024 + j1) * 256;
  const float* uu0 = &whh_s[(size_t)(0  + jj) * 516];
  const float* uu1 = &whh_s[(size_t)(16 + jj) * 516];
  const float* uu2 = &whh_s[(size_t)(32 + jj) * 516];
  const float* wq = a.WqT  + (size_t)j1 * 512;
  const float* hrow = &h_s[bi8 * 516];

  unsigned epoch = 0;

  for (int t = 0; t < STEPS; ++t) {
    float* hcur = (t & 1) ? a.h1 : a.h0;
    float* hnxt = (t & 1) ? a.h0 : a.h1;

    // ================= P1: GRU -> h_new =================
    {
      // stage hcur[bb*8 .. +8][:] (16KB) + idx into LDS (agent-scope, once per WG)
      const unsigned long long* hs64 = (const unsigned long long*)hcur + (size_t)bb * 2048;
      {
        unsigned long long v0 = ld_sc64(hs64 + tid);
        unsigned long long v1 = ld_sc64(hs64 + tid + 1024);
        int r0i = tid >> 8,          c0 = (tid & 255) * 2;
        int r1i = (tid + 1024) >> 8, c1 = (tid & 255) * 2;
        h_s[r0i * 516 + c0] = u_lo(v0); h_s[r0i * 516 + c0 + 1] = u_hi(v0);
        h_s[r1i * 516 + c1] = u_lo(v1); h_s[r1i * 516 + c1 + 1] = u_hi(v1);
      }
      if (tid < 8) s_idx[tid] = (int)((~(unsigned)ld_sc64(&a.amax[bb * 8 + tid])) & 511u);
      __syncthreads();

      const int idx = s_idx[bi8];
      const float* xrow = a.inputs + ((size_t)idx * 64 + (bb * 8 + bi8)) * 256;
      float s0 = 0.f, s1 = 0.f, s2 = 0.f, s3 = 0.f;
#pragma unroll
      for (int k = ks * 32; k < ks * 32 + 32; k += 4) {
        float4 xv = *(const float4*)&xrow[k];
        float4 c0 = *(const float4*)&w0[k];
        float4 c1 = *(const float4*)&w1[k];
        float4 c2 = *(const float4*)&w2[k];
        s0 += xv.x * c0.x + xv.y * c0.y + xv.z * c0.z + xv.w * c0.w;
        s1 += xv.x * c1.x + xv.y * c1.y + xv.z * c1.z + xv.w * c1.w;
        s2 += xv.x * c2.x + xv.y * c2.y + xv.z * c2.z + xv.w * c2.w;
      }
#pragma unroll 4
      for (int k = ks * 64; k < ks * 64 + 64; k += 4) {
        float4 h4 = *(const float4*)&hrow[k];
        float4 c0 = *(const float4*)&uu0[k];
        float4 c1 = *(const float4*)&uu1[k];
        float4 c2 = *(const float4*)&uu2[k];
        s0 += h4.x * c0.x + h4.y * c0.y + h4.z * c0.z + h4.w * c0.w;
        s1 += h4.x * c1.x + h4.y * c1.y + h4.z * c1.z + h4.w * c1.w;
        s3 += h4.x * c2.x + h4.y * c2.y + h4.z * c2.z + h4.w * c2.w;
      }
      *(float4*)&sred[(size_t)((ks * 8 + bi8) * 16 + jj) * 4] = make_float4(s0, s1, s2, s3);
      __syncthreads();
      if (tid < 128) {
        int bi = tid >> 4, j2 = tid & 15;
        float4 acc4 = make_float4(0.f, 0.f, 0.f, 0.f);
#pragma unroll
        for (int kk = 0; kk < 8; ++kk) {
          float4 vv = *(float4*)&sred[(size_t)((kk * 8 + bi) * 16 + j2) * 4];
          acc4.x += vv.x; acc4.y += vv.y; acc4.z += vv.z; acc4.w += vv.w;
        }
        int b = bb * 8 + bi, j = jb * 16 + j2;
        float r = fast_sig(acc4.x + a.bc[j] + a.b_hh[j]);
        float z = fast_sig(acc4.y + a.bc[512 + j] + a.b_hh[512 + j]);
        float n = fast_tanh(acc4.z + a.bc[1024 + j] + r * (acc4.w + a.b_hh[1024 + j]));
        float hv = h_s[bi * 516 + j];
        st_sc(&hnxt[b * 512 + j], (1.f - z) * n + z * hv);
      }
    }
    gridbar(a.bar, epoch, w);

    // ================= P2: q = h_new @ W_q  (+ amax reset) =================
    {
      const unsigned long long* hs64 = (const unsigned long long*)hnxt + (size_t)bb * 2048;
      {
        unsigned long long v0 = ld_sc64(hs64 + tid);
        unsigned long long v1 = ld_sc64(hs64 + tid + 1024);
        int r0i = tid >> 8,          c0 = (tid & 255) * 2;
        int r1i = (tid + 1024) >> 8, c1 = (tid & 255) * 2;
        h_s[r0i * 516 + c0] = u_lo(v0); h_s[r0i * 516 + c0 + 1] = u_hi(v0);
        h_s[r1i * 516 + c1] = u_lo(v1); h_s[r1i * 516 + c1 + 1] = u_hi(v1);
      }
      __syncthreads();
      float s = 0.f;
#pragma unroll 4
      for (int k = ks * 64; k < ks * 64 + 64; k += 4) {
        float4 h4 = *(const float4*)&hrow[k];
        float4 c4 = *(const float4*)&wq[k];
        s += h4.x * c4.x + h4.y * c4.y + h4.z * c4.z + h4.w * c4.w;
      }
      sred[(ks * 8 + bi8) * 16 + jj] = s;
      __syncthreads();
      if (tid < 128) {
        int bi = tid >> 4, ii = tid & 15;
        float acc = 0.f;
#pragma unroll
        for (int kk = 0; kk < 8; ++kk) acc += sred[(kk * 8 + bi) * 16 + ii];
        st_sc(&a.q[(bb * 8 + bi) * 512 + jb * 16 + ii], acc);
      }
      if (jb == 0 && tid < 8) st_sc64(&a.amax[bb * 8 + tid], 0ULL);
    }
    gridbar(a.bar, epoch, w);

    // ================= P3: attention scores + logits + argmax =================
    {
      if (tid < 256) {
        unsigned long long qu = ld_sc64(&a.q[b3 * 512 + tid * 2]);
        q_s[tid * 2] = u_lo(qu); q_s[tid * 2 + 1] = u_hi(qu);
      }
      __syncthreads();
      float4 qA = *(const float4*)&q_s[lane * 4];
      float4 qB = *(const float4*)&q_s[256 + lane * 4];
      // issue all 16 row-loads up front (short live range, within-phase only)
      f4v rA0 = *(const f4v*)(ekp + 0 * 512), rB0 = *(const f4v*)(ekp + 0 * 512 + 256);
      f4v rA1 = *(const f4v*)(ekp + 1 * 512), rB1 = *(const f4v*)(ekp + 1 * 512 + 256);
      f4v rA2 = *(const f4v*)(ekp + 2 * 512), rB2 = *(const f4v*)(ekp + 2 * 512 + 256);
      f4v rA3 = *(const f4v*)(ekp + 3 * 512), rB3 = *(const f4v*)(ekp + 3 * 512 + 256);
      f4v rA4 = *(const f4v*)(ekp + 4 * 512), rB4 = *(const f4v*)(ekp + 4 * 512 + 256);
      f4v rA5 = *(const f4v*)(ekp + 5 * 512), rB5 = *(const f4v*)(ekp + 5 * 512 + 256);
      f4v rA6 = *(const f4v*)(ekp + 6 * 512), rB6 = *(const f4v*)(ekp + 6 * 512 + 256);
      f4v rA7 = *(const f4v*)(ekp + 7 * 512), rB7 = *(const f4v*)(ekp + 7 * 512 + 256);
      float s0, s1, s2, s3, s4, s5, s6, s7;
#define ROW(PA, PB, S) { float acc; \
      acc  = fast_tanh(qA.x + PA.x) * vA.x; \
      acc += fast_tanh(qA.y + PA.y) * vA.y; \
      acc += fast_tanh(qA.z + PA.z) * vA.z; \
      acc += fast_tanh(qA.w + PA.w) * vA.w; \
      acc += fast_tanh(qB.x + PB.x) * vB.x; \
      acc += fast_tanh(qB.y + PB.y) * vB.y; \
      acc += fast_tanh(qB.z + PB.z) * vB.z; \
      acc += fast_tanh(qB.w + PB.w) * vB.w; \
      _Pragma("unroll") \
      for (int m = 1; m < 64; m <<= 1) acc += __shfl_xor(acc, m, 64); \
      S = acc; }
      ROW(rA0, rB0, s0) ROW(rA1, rB1, s1) ROW(rA2, rB2, s2) ROW(rA3, rB3, s3)
      ROW(rA4, rB4, s4) ROW(rA5, rB5, s5) ROW(rA6, rB6, s6) ROW(rA7, rB7, s7)
#undef ROW
      if (lane == 0) {
        size_t off = ((size_t)t * 64 + b3) * 512 + (size_t)(lt * 128 + wv * 8);
        *(float4*)&a.out[off]     = make_float4(s0, s1, s2, s3);
        *(float4*)&a.out[off + 4] = make_float4(s4, s5, s6, s7);
        float best = s0; int bu = 0;
        if (s1 > best) { best = s1; bu = 1; }
        if (s2 > best) { best = s2; bu = 2; }
        if (s3 > best) { best = s3; bu = 3; }
        if (s4 > best) { best = s4; bu = 4; }
        if (s5 > best) { best = s5; bu = 5; }
        if (s6 > best) { best = s6; bu = 6; }
        if (s7 > best) { best = s7; bu = 7; }
        unsigned bits = __float_as_uint(best);
        unsigned key  = bits ^ ((bits & 0x80000000u) ? 0xFFFFFFFFu : 0x80000000u);
        unsigned ll   = (unsigned)(lt * 128 + wv * 8 + bu);
        su64[wv] = ((unsigned long long)key << 32) | (unsigned)(~ll);
      }
      __syncthreads();
      if (tid == 0) {
        unsigned long long m = su64[0];
#pragma unroll
        for (int i = 1; i < 16; ++i) if (su64[i] > m) m = su64[i];
        __hip_atomic_fetch_max(&a.amax[b3], m, __ATOMIC_RELAXED, __HIP_MEMORY_SCOPE_AGENT);
      }
    }
    gridbar(a.bar, epoch, w);
  }
}

// ---------------- launcher ----------------
extern "C" void kernel_launch(void* const* d_in, const int* in_sizes, int n_in,
                              void* d_out, int out_size, void* d_ws, size_t ws_size,
                              hipStream_t stream) {
  (void)in_sizes; (void)n_in; (void)out_size;
  if (ws_size < WS_NEED) return;

  const float* inputs  = (const float*)d_in[0];
  const float* enc_out = (const float*)d_in[2];
  const float* enc_hid = (const float*)d_in[3];
  const float* W_lin   = (const float*)d_in[4];
  const float* b_lin   = (const float*)d_in[5];
  const float* W_ih    = (const float*)d_in[6];
  const float* W_hh    = (const float*)d_in[7];
  const float* b_ih    = (const float*)d_in[8];
  const float* b_hh    = (const float*)d_in[9];
  const float* W_q     = (const float*)d_in[10];
  const float* W_k     = (const float*)d_in[11];
  const float* v_att   = (const float*)d_in[12];

  char* ws = (char*)d_ws;
  float* ekT  = (float*)(ws + OFF_EKT);
  float* WcT  = (float*)(ws + OFF_WCT);
  float* bc   = (float*)(ws + OFF_BC);
  float* WhhT = (float*)(ws + OFF_WHHT);
  float* WqT  = (float*)(ws + OFF_WQT);
  float* h0   = (float*)(ws + OFF_H0);
  float* h1   = (float*)(ws + OFF_H1);
  float* q    = (float*)(ws + OFF_Q);
  unsigned long long* amax = (unsigned long long*)(ws + OFF_AMAX);
  unsigned* bar = (unsigned*)(ws + OFF_BAR);

  initk<<<dim3(128), dim3(256), 0, stream>>>(enc_hid, h0, amax, bar);
  bck<<<dim3(6), dim3(256), 0, stream>>>(b_lin, W_ih, b_ih, bc);
  trk<<<dim3((512 * 1536 + 255) / 256), dim3(256), 0, stream>>>(W_hh, WhhT, 512, 1536);
  trk<<<dim3((512 * 512 + 255) / 256), dim3(256), 0, stream>>>(W_q, WqT, 512, 512);
  gemm64<<<dim3(4, 24), dim3(256), 0, stream>>>(W_lin, W_ih, WcT, 512, 512, 1536, 2, 1536);
  gemm64<<<dim3(512, 8), dim3(256), 0, stream>>>(enc_out, W_k, ekT, 512, 512, 512, 1, 512);

  CoopArgs ca;
  ca.inputs = inputs; ca.b_hh = b_hh; ca.ekT = ekT;
  ca.WcT = WcT; ca.bc = bc; ca.WhhT = WhhT; ca.WqT = WqT;
  ca.v_att = v_att;
  ca.h0 = h0; ca.h1 = h1; ca.q = q;
  ca.amax = amax; ca.bar = bar;
  ca.out = (float*)d_out;

  void* args[] = { &ca };
  hipLaunchCooperativeKernel((const void*)decoder, dim3(NWG), dim3(NTHR), args, 0, stream);
}